// Round 11
// baseline (115.099 us; speedup 1.0000x reference)
//
#include <hip/hip_runtime.h>
#include <hip/hip_bf16.h>

// MoE gate (DeepSeek-V2 style): logits = X @ W^T, softmax, group-limited
// top-3-of-8 groups, top-6 experts, normalized weights (sorted desc).
//
// X: [T=32768, H=2048] fp32   W: [64, 2048] fp32   out: [T, 6] fp32
//
// Precision (r9, verified): fp32 = hi+lo FP16 (22 mantissa bits; residual
// split exact; dropped lo*lo ~2^-22). 3 MFMA passes (hh, hl, lh).
//
// Round-11 change vs r9 (72us): N-SPLIT x2 INSIDE the block -> 4 waves/SIMD
// with zero extra HBM traffic. Wave (tm, en) owns 16 tokens x 32 experts
// (1 M-frag x 2 N-frags): waves double to 4096 (2 blocks/CU x 8 waves),
// per-wave state shrinks (acc 8, B-reads 4/step, MFMA 6/step) -> fits the
// 128-VGPR cap of (512,4) without spill. Per-CU A-bytes / LDS ops / MFMA
// unchanged; only B L2 re-reads double (~8us aggregate). Epilogue merges
// the two expert-halves through LDS with one __syncthreads.
// Skeleton unchanged: K-128 chunks, 4-deep A-ring (never vmcnt-drained),
// B staged to LDS issue-early/write-late, lane*16B slots, lgkm-only barriers.

#define HD 2048
#define NE 64
#define NCH 16       // K-chunks of 128
#define BUFB 32768   // bytes per LDS B buffer: 4 steps * 2 splits * 4KB

typedef __attribute__((ext_vector_type(4))) float f4;
typedef __attribute__((ext_vector_type(8))) short s8;
typedef __attribute__((ext_vector_type(8))) _Float16 h8;
typedef __attribute__((ext_vector_type(4))) float accv;
typedef unsigned short u16;

// fp32 -> hi/lo fp16 split (RNE; residual exact; dropped term ~2^-22).
__device__ __forceinline__ void split8h(const f4 v0, const f4 v1, s8& h, s8& l) {
  #pragma unroll
  for (int i = 0; i < 8; ++i) {
    float a = (i < 4) ? v0[i] : v1[i - 4];
    _Float16 hh = (_Float16)a;
    float r = a - (float)hh;
    _Float16 ll = (_Float16)r;
    h[i] = __builtin_bit_cast(short, hh);
    l[i] = __builtin_bit_cast(short, ll);
  }
}

__device__ __forceinline__ accv mfma3(s8 ah, s8 al, s8 bh, s8 bl, accv t) {
  h8 AH = __builtin_bit_cast(h8, ah);
  h8 AL = __builtin_bit_cast(h8, al);
  h8 BH = __builtin_bit_cast(h8, bh);
  h8 BL = __builtin_bit_cast(h8, bl);
  t = __builtin_amdgcn_mfma_f32_16x16x32_f16(AH, BH, t, 0, 0, 0);
  t = __builtin_amdgcn_mfma_f32_16x16x32_f16(AH, BL, t, 0, 0, 0);
  t = __builtin_amdgcn_mfma_f32_16x16x32_f16(AL, BH, t, 0, 0, 0);
  return t;
}

// Shared epilogue: v[64] logits -> top-3 groups -> top-6 -> normalized weights.
__device__ __forceinline__ void epilogue64(const float* v, float* op) {
  float gm[8];
  #pragma unroll
  for (int g = 0; g < 8; ++g) {
    float mx = v[g * 8];
    #pragma unroll
    for (int j = 1; j < 8; ++j) mx = fmaxf(mx, v[g * 8 + j]);
    gm[g] = mx;
  }
  unsigned selmask = 0u;
  #pragma unroll
  for (int itg = 0; itg < 3; ++itg) {
    float best = gm[0];
    #pragma unroll
    for (int g = 1; g < 8; ++g) best = fmaxf(best, gm[g]);
    int bi = 7;
    #pragma unroll
    for (int g = 6; g >= 0; --g)
      if (gm[g] == best) bi = g;
    selmask |= (1u << bi);
    #pragma unroll
    for (int g = 0; g < 8; ++g) gm[g] = (g == bi) ? -3.0e38f : gm[g];
  }
  float t0 = -3.0e38f, t1 = -3.0e38f, t2 = -3.0e38f;
  float t3 = -3.0e38f, t4 = -3.0e38f, t5 = -3.0e38f;
  #pragma unroll
  for (int g = 0; g < 8; ++g) {
    const bool sel = (selmask >> g) & 1u;
    #pragma unroll
    for (int j = 0; j < 8; ++j) {
      float x = sel ? v[g * 8 + j] : -3.0e38f;
      float mm;
      mm = fmaxf(t0, x); x = fminf(t0, x); t0 = mm;
      mm = fmaxf(t1, x); x = fminf(t1, x); t1 = mm;
      mm = fmaxf(t2, x); x = fminf(t2, x); t2 = mm;
      mm = fmaxf(t3, x); x = fminf(t3, x); t3 = mm;
      mm = fmaxf(t4, x); x = fminf(t4, x); t4 = mm;
      t5 = fmaxf(t5, x);
    }
  }
  float e0 = 1.0f;
  float e1 = __expf(t1 - t0);
  float e2 = __expf(t2 - t0);
  float e3 = __expf(t3 - t0);
  float e4 = __expf(t4 - t0);
  float e5 = __expf(t5 - t0);
  float sum = e0 + e1 + e2 + e3 + e4 + e5;
  float inv = 1.0f / sum;
  op[0] = e0 * inv; op[1] = e1 * inv; op[2] = e2 * inv;
  op[3] = e3 * inv; op[4] = e4 * inv; op[5] = e5 * inv;
}

// ---- kernel 1: split gate weights fp32 -> {hi,lo} fp16 in d_ws ------------
__global__ __launch_bounds__(256) void cvtW2(const float* __restrict__ Wf,
                                             u16* __restrict__ Wh,
                                             u16* __restrict__ Wl) {
  int i = (blockIdx.x * 256 + threadIdx.x) * 8;  // 64 blocks cover 131072
  f4 v0 = *(const f4*)(Wf + i);
  f4 v1 = *(const f4*)(Wf + i + 4);
  s8 h, l;
  split8h(v0, v1, h, l);
  *(s8*)((short*)Wh + i) = h;
  *(s8*)((short*)Wl + i) = l;
}

// ---- kernel 2: fused gate (fp16 2-split, 16tok x 32exp waves, 4 w/SIMD) ----
template <bool PRE>
__global__ __launch_bounds__(512, 4) void gateF(
    const float* __restrict__ X, const float* __restrict__ Wf,
    const u16* __restrict__ Wh, const u16* __restrict__ Wl,
    float* __restrict__ out) {
  __shared__ __align__(16) unsigned char smem[2 * BUFB];  // 64 KB

  const int tid = threadIdx.x;
  const int lane = tid & 63;
  const int w = tid >> 6;    // wave 0..7
  const int tm = w >> 1;     // token-tile 0..3 (16 tokens each)
  const int en = w & 1;      // expert-half 0..1 (32 experts each)
  const int ec = lane & 15;  // token row (A) / expert col (B)
  const int kg = lane >> 4;  // 0..3 (8 consecutive k)
  const int tok0 = blockIdx.x * 64;

  // A stream: this wave's 16 token rows
  const float* pA = X + (size_t)(tok0 + tm * 16 + ec) * HD + kg * 8;

  // staging roles: wave w stages step st=tm, expert-groups sgA=2en, sgB=2en+1
  const int sgA = 2 * en, sgB = 2 * en + 1;
  const size_t wsrcA = (size_t)(sgA * 16 + ec) * HD + tm * 32 + kg * 8;
  const size_t wsrcB = (size_t)(sgB * 16 + ec) * HD + tm * 32 + kg * 8;
  // LDS dst byte offset: st*8192 + split*4096 + sg*1024 + lane*16
  const int sdstA = tm * 8192 + sgA * 1024 + lane * 16;  // split0; split1 +4096
  const int sdstB = tm * 8192 + sgB * 1024 + lane * 16;

  accv acc[2];
  acc[0] = (accv){0.f, 0.f, 0.f, 0.f};
  acc[1] = (accv){0.f, 0.f, 0.f, 0.f};

  f4 ar[4][2];  // A raw ring, 4-step lookahead (static slots)

  // --- prologue: stage chunk 0 into buf0; prefetch A steps 0..3 ---
  {
    s8 th, tl;
    f4 r0, r1;
    if constexpr (PRE) {
      th = *(const s8*)(Wh + wsrcA);
      tl = *(const s8*)(Wl + wsrcA);
    } else {
      r0 = *(const f4*)(Wf + wsrcA);
      r1 = *(const f4*)(Wf + wsrcA + 4);
      split8h(r0, r1, th, tl);
    }
    unsigned char* d = smem + sdstA;
    *(s8*)(d) = th;
    *(s8*)(d + 4096) = tl;
    if constexpr (PRE) {
      th = *(const s8*)(Wh + wsrcB);
      tl = *(const s8*)(Wl + wsrcB);
    } else {
      r0 = *(const f4*)(Wf + wsrcB);
      r1 = *(const f4*)(Wf + wsrcB + 4);
      split8h(r0, r1, th, tl);
    }
    d = smem + sdstB;
    *(s8*)(d) = th;
    *(s8*)(d + 4096) = tl;
  }
  #pragma unroll
  for (int st = 0; st < 4; ++st) {
    ar[st][0] = *(const f4*)(pA + st * 32);
    ar[st][1] = *(const f4*)(pA + st * 32 + 4);
  }
  asm volatile("s_waitcnt lgkmcnt(0)");
  __builtin_amdgcn_s_barrier();
  __builtin_amdgcn_sched_barrier(0);

  // --- main loop: 16 chunks of K=128 (4 MFMA-steps each) ---
  for (int c = 0; c < NCH; ++c) {
    const unsigned char* rb = smem + (c & 1) * BUFB;
    unsigned char* wb = smem + ((c + 1) & 1) * BUFB;
    const bool do_stage = (c + 1 < NCH);

    // issue next-chunk B loads NOW (written to LDS after compute: T14 split)
    s8 thA, tlA, thB, tlB;
    f4 qA0, qA1, qB0, qB1;
    if (do_stage) {
      const size_t oA = wsrcA + (size_t)(c + 1) * 128;
      const size_t oB = wsrcB + (size_t)(c + 1) * 128;
      if constexpr (PRE) {
        thA = *(const s8*)(Wh + oA);
        tlA = *(const s8*)(Wl + oA);
        thB = *(const s8*)(Wh + oB);
        tlB = *(const s8*)(Wl + oB);
      } else {
        qA0 = *(const f4*)(Wf + oA);
        qA1 = *(const f4*)(Wf + oA + 4);
        qB0 = *(const f4*)(Wf + oB);
        qB1 = *(const f4*)(Wf + oB + 4);
      }
    }

    #pragma unroll
    for (int st = 0; st < 4; ++st) {
      const int t = c * 4 + st;
      s8 ah, al;
      split8h(ar[st][0], ar[st][1], ah, al);
      const int tn = (t + 4 < 64) ? (t + 4) : 63;  // clamp; dup load harmless
      ar[st][0] = *(const f4*)(pA + tn * 32);
      ar[st][1] = *(const f4*)(pA + tn * 32 + 4);
      #pragma unroll
      for (int f = 0; f < 2; ++f) {
        const unsigned char* bp = rb + st * 8192 + (2 * en + f) * 1024 + lane * 16;
        s8 bh = *(const s8*)(bp);
        s8 bl = *(const s8*)(bp + 4096);
        acc[f] = mfma3(ah, al, bh, bl, acc[f]);
      }
    }

    // write staged B (loads have had 4 steps to land)
    if (do_stage) {
      if constexpr (!PRE) {
        split8h(qA0, qA1, thA, tlA);
        split8h(qB0, qB1, thB, tlB);
      }
      unsigned char* d = wb + sdstA;
      *(s8*)(d) = thA;
      *(s8*)(d + 4096) = tlA;
      d = wb + sdstB;
      *(s8*)(d) = thB;
      *(s8*)(d + 4096) = tlB;
    }
    // boundary: LDS-only drain; A vmcnt stream NEVER drained
    __builtin_amdgcn_sched_barrier(0);
    asm volatile("s_waitcnt lgkmcnt(0)");
    __builtin_amdgcn_s_barrier();
    __builtin_amdgcn_sched_barrier(0);
  }

  // --- epilogue: merge expert-halves through LDS ---
  // lf[64 tok][68]: row = tm*16 + kg*4 + r, col = en*32 + f*16 + ec
  float* lf = (float*)smem;
  #pragma unroll
  for (int f = 0; f < 2; ++f)
    #pragma unroll
    for (int r = 0; r < 4; ++r)
      lf[(tm * 16 + kg * 4 + r) * 68 + en * 32 + f * 16 + ec] = acc[f][r];
  __syncthreads();

  if (lane < 8) {
    const int t = w * 8 + lane;
    float v[64];
    #pragma unroll
    for (int i = 0; i < 16; ++i) {
      f4 q = *(const f4*)(lf + t * 68 + 4 * i);
      v[4 * i + 0] = q.x; v[4 * i + 1] = q.y;
      v[4 * i + 2] = q.z; v[4 * i + 3] = q.w;
    }
    epilogue64(v, out + (size_t)(tok0 + t) * 6);
  }
}

extern "C" void kernel_launch(void* const* d_in, const int* in_sizes, int n_in,
                              void* d_out, int out_size, void* d_ws, size_t ws_size,
                              hipStream_t stream) {
  const float* X = (const float*)d_in[0];
  const float* Wf = (const float*)d_in[1];
  float* out = (float*)d_out;
  const int T = in_sizes[0] / HD;  // 32768
  const int nblk = T / 64;         // 512 blocks of 512 threads (8 waves)

  const size_t need = (size_t)NE * HD * sizeof(u16);  // 256 KB per split
  if (ws_size >= 2 * need) {
    u16* Whi = (u16*)d_ws;
    u16* Wlo = Whi + (size_t)NE * HD;
    cvtW2<<<dim3(64), dim3(256), 0, stream>>>(Wf, Whi, Wlo);
    gateF<true><<<dim3(nblk), dim3(512), 0, stream>>>(X, Wf, Whi, Wlo, out);
  } else {
    gateF<false><<<dim3(nblk), dim3(512), 0, stream>>>(X, Wf, nullptr, nullptr, out);
  }
}

// Round 12
// 67.144 us; speedup vs baseline: 1.7142x; 1.7142x over previous
//
#include <hip/hip_runtime.h>
#include <hip/hip_bf16.h>

// MoE gate (DeepSeek-V2 style): logits = X @ W^T, softmax, group-limited
// top-3-of-8 groups, top-6 experts, normalized weights (sorted desc).
//
// X: [T=32768, H=2048] fp32   W: [64, 2048] fp32   out: [T, 6] fp32
//
// Precision (r9, verified): fp32 = hi+lo FP16 (22 mantissa bits; residual
// split exact; dropped lo*lo ~2^-22). 3 MFMA passes (hh, hl, lh).
//
// Round-12 changes vs r9 (72us): cut chunk-boundary overhead, keep the
// proven counter-separation (A on vmcnt with 4-step slack; B staging
// proven complete via COUNTED vmcnt, not a drain):
//  - B staged with global_load_lds width=16 (dst = wave-uniform + lane*16,
//    exactly our layout): no B regs, no ds_writes, no lgkm stage-drain.
//  - Chunk barrier: s_waitcnt vmcnt(16) -- 16 = A-loads issued after the
//    8 stage instrs, so stage(c+1) is complete while the newest 16 A
//    prefetches stay in flight. lgkmcnt(0) added (reads already consumed).
//  - K-256 chunks (8 steps): 8 barriers total (was 16). LDS 2x64KB=128KB.
//  - cvtW2 widened to 256 blocks.

#define HD 2048
#define NE 64
#define NCH 8        // K-chunks of 256
#define BUFB 65536   // bytes per LDS B buffer: 8 steps * 2 splits * 4KB

typedef __attribute__((ext_vector_type(4))) float f4;
typedef __attribute__((ext_vector_type(8))) short s8;
typedef __attribute__((ext_vector_type(8))) _Float16 h8;
typedef __attribute__((ext_vector_type(4))) float accv;
typedef unsigned short u16;

// fp32 -> hi/lo fp16 split (RNE; residual exact; dropped term ~2^-22).
__device__ __forceinline__ void split8h(const f4 v0, const f4 v1, s8& h, s8& l) {
  #pragma unroll
  for (int i = 0; i < 8; ++i) {
    float a = (i < 4) ? v0[i] : v1[i - 4];
    _Float16 hh = (_Float16)a;
    float r = a - (float)hh;
    _Float16 ll = (_Float16)r;
    h[i] = __builtin_bit_cast(short, hh);
    l[i] = __builtin_bit_cast(short, ll);
  }
}

__device__ __forceinline__ accv mfma3(s8 ah, s8 al, s8 bh, s8 bl, accv t) {
  h8 AH = __builtin_bit_cast(h8, ah);
  h8 AL = __builtin_bit_cast(h8, al);
  h8 BH = __builtin_bit_cast(h8, bh);
  h8 BL = __builtin_bit_cast(h8, bl);
  t = __builtin_amdgcn_mfma_f32_16x16x32_f16(AH, BH, t, 0, 0, 0);
  t = __builtin_amdgcn_mfma_f32_16x16x32_f16(AH, BL, t, 0, 0, 0);
  t = __builtin_amdgcn_mfma_f32_16x16x32_f16(AL, BH, t, 0, 0, 0);
  return t;
}

// Shared epilogue: v[64] logits -> top-3 groups -> top-6 -> normalized weights.
__device__ __forceinline__ void epilogue64(const float* v, float* op) {
  float gm[8];
  #pragma unroll
  for (int g = 0; g < 8; ++g) {
    float mx = v[g * 8];
    #pragma unroll
    for (int j = 1; j < 8; ++j) mx = fmaxf(mx, v[g * 8 + j]);
    gm[g] = mx;
  }
  unsigned selmask = 0u;
  #pragma unroll
  for (int itg = 0; itg < 3; ++itg) {
    float best = gm[0];
    #pragma unroll
    for (int g = 1; g < 8; ++g) best = fmaxf(best, gm[g]);
    int bi = 7;
    #pragma unroll
    for (int g = 6; g >= 0; --g)
      if (gm[g] == best) bi = g;
    selmask |= (1u << bi);
    #pragma unroll
    for (int g = 0; g < 8; ++g) gm[g] = (g == bi) ? -3.0e38f : gm[g];
  }
  float t0 = -3.0e38f, t1 = -3.0e38f, t2 = -3.0e38f;
  float t3 = -3.0e38f, t4 = -3.0e38f, t5 = -3.0e38f;
  #pragma unroll
  for (int g = 0; g < 8; ++g) {
    const bool sel = (selmask >> g) & 1u;
    #pragma unroll
    for (int j = 0; j < 8; ++j) {
      float x = sel ? v[g * 8 + j] : -3.0e38f;
      float mm;
      mm = fmaxf(t0, x); x = fminf(t0, x); t0 = mm;
      mm = fmaxf(t1, x); x = fminf(t1, x); t1 = mm;
      mm = fmaxf(t2, x); x = fminf(t2, x); t2 = mm;
      mm = fmaxf(t3, x); x = fminf(t3, x); t3 = mm;
      mm = fmaxf(t4, x); x = fminf(t4, x); t4 = mm;
      t5 = fmaxf(t5, x);
    }
  }
  float e0 = 1.0f;
  float e1 = __expf(t1 - t0);
  float e2 = __expf(t2 - t0);
  float e3 = __expf(t3 - t0);
  float e4 = __expf(t4 - t0);
  float e5 = __expf(t5 - t0);
  float sum = e0 + e1 + e2 + e3 + e4 + e5;
  float inv = 1.0f / sum;
  op[0] = e0 * inv; op[1] = e1 * inv; op[2] = e2 * inv;
  op[3] = e3 * inv; op[4] = e4 * inv; op[5] = e5 * inv;
}

// ---- kernel 1: split gate weights fp32 -> {hi,lo} fp16 in d_ws ------------
__global__ __launch_bounds__(64) void cvtW2(const float* __restrict__ Wf,
                                            u16* __restrict__ Wh,
                                            u16* __restrict__ Wl) {
  int i = (blockIdx.x * 64 + threadIdx.x) * 8;  // 256 blocks cover 131072
  f4 v0 = *(const f4*)(Wf + i);
  f4 v1 = *(const f4*)(Wf + i + 4);
  s8 h, l;
  split8h(v0, v1, h, l);
  *(s8*)((short*)Wh + i) = h;
  *(s8*)((short*)Wl + i) = l;
}

// ---- kernel 2: fused gate (fp16 2-split, gl_lds staging, K-256 chunks) -----
template <bool PRE>
__global__ __launch_bounds__(512, 2) void gateF(
    const float* __restrict__ X, const float* __restrict__ Wf,
    const u16* __restrict__ Wh, const u16* __restrict__ Wl,
    float* __restrict__ out) {
  __shared__ __align__(16) unsigned char smem[2 * BUFB];  // 128 KB

  const int tid = threadIdx.x;
  const int lane = tid & 63;
  const int w = tid >> 6;      // wave 0..7 -> owns tokens tok0 + w*16 ..
  const int ec = lane & 15;    // token row (A) / expert col (B)
  const int kg = lane >> 4;    // 0..3 (8 consecutive k)
  const int tok0 = blockIdx.x * 128;

  // A stream: this wave's 16 token rows
  const float* pA = X + (size_t)(tok0 + w * 16 + ec) * HD + kg * 8;

  // staging role: wave w stages step-in-chunk st=w, all 4 expert groups j,
  // both splits. src: (j*16+ec)*HD + w*32 + kg*8 (+ c*256 per chunk).
  // dst byte: buf + w*8192 + split*4096 + j*1024 + lane*16.
  const size_t wsrcb = (size_t)ec * HD + w * 32 + kg * 8;
  const int sdstb = w * 8192 + lane * 16;

  accv acc[4];
  #pragma unroll
  for (int f = 0; f < 4; ++f) acc[f] = (accv){0.f, 0.f, 0.f, 0.f};

  f4 ar[4][2];  // A raw ring, 4-step lookahead (static slots)

  // --- prologue: stage chunk 0 into buf0; prefetch A steps 0..3 ---
  if constexpr (PRE) {
    #pragma unroll
    for (int j = 0; j < 4; ++j) {
      const size_t o = wsrcb + (size_t)j * 16 * HD;
      __builtin_amdgcn_global_load_lds((const unsigned int*)(Wh + o),
                                       (unsigned int*)(smem + sdstb + j * 1024), 16, 0, 0);
      __builtin_amdgcn_global_load_lds((const unsigned int*)(Wl + o),
                                       (unsigned int*)(smem + sdstb + 4096 + j * 1024), 16, 0, 0);
    }
  } else {
    #pragma unroll
    for (int j = 0; j < 4; ++j) {
      const size_t o = wsrcb + (size_t)j * 16 * HD;
      f4 r0 = *(const f4*)(Wf + o);
      f4 r1 = *(const f4*)(Wf + o + 4);
      s8 th, tl;
      split8h(r0, r1, th, tl);
      *(s8*)(smem + sdstb + j * 1024) = th;
      *(s8*)(smem + sdstb + 4096 + j * 1024) = tl;
    }
  }
  __builtin_amdgcn_sched_barrier(0);
  #pragma unroll
  for (int st = 0; st < 4; ++st) {
    ar[st][0] = *(const f4*)(pA + st * 32);
    ar[st][1] = *(const f4*)(pA + st * 32 + 4);
  }
  __builtin_amdgcn_sched_barrier(0);
  if constexpr (PRE) {
    asm volatile("s_waitcnt vmcnt(8) lgkmcnt(0)");  // stage done; 8 A-loads fly
  } else {
    asm volatile("s_waitcnt lgkmcnt(0)");
  }
  __builtin_amdgcn_s_barrier();
  __builtin_amdgcn_sched_barrier(0);

  // --- main loop: 8 chunks of K=256 (8 MFMA-steps each) ---
  for (int c = 0; c < NCH; ++c) {
    const unsigned char* rb = smem + (c & 1) * BUFB;
    unsigned char* wb = smem + ((c + 1) & 1) * BUFB;
    const bool do_stage = (c + 1 < NCH);

    // issue next-chunk B stage NOW (global_load_lds: lands during compute)
    f4 q0[4], q1[4];  // only used by !PRE fallback
    if (do_stage) {
      if constexpr (PRE) {
        #pragma unroll
        for (int j = 0; j < 4; ++j) {
          const size_t o = wsrcb + (size_t)j * 16 * HD + (size_t)(c + 1) * 256;
          __builtin_amdgcn_global_load_lds((const unsigned int*)(Wh + o),
                                           (unsigned int*)(wb + sdstb + j * 1024), 16, 0, 0);
          __builtin_amdgcn_global_load_lds((const unsigned int*)(Wl + o),
                                           (unsigned int*)(wb + sdstb + 4096 + j * 1024), 16, 0, 0);
        }
      } else {
        #pragma unroll
        for (int j = 0; j < 4; ++j) {
          const size_t o = wsrcb + (size_t)j * 16 * HD + (size_t)(c + 1) * 256;
          q0[j] = *(const f4*)(Wf + o);
          q1[j] = *(const f4*)(Wf + o + 4);
        }
      }
    }
    __builtin_amdgcn_sched_barrier(0);

    #pragma unroll
    for (int st = 0; st < 8; ++st) {
      const int t = c * 8 + st;
      s8 ah, al;
      split8h(ar[st & 3][0], ar[st & 3][1], ah, al);
      const int tn = (t + 4 < 64) ? (t + 4) : 63;  // clamp; dup load harmless
      ar[st & 3][0] = *(const f4*)(pA + tn * 32);
      ar[st & 3][1] = *(const f4*)(pA + tn * 32 + 4);
      #pragma unroll
      for (int f = 0; f < 4; ++f) {
        const unsigned char* bp = rb + st * 8192 + f * 1024 + lane * 16;
        s8 bh = *(const s8*)(bp);
        s8 bl = *(const s8*)(bp + 4096);
        acc[f] = mfma3(ah, al, bh, bl, acc[f]);
      }
    }

    // !PRE fallback: write staged B now (loads have had 8 steps to land)
    if (do_stage) {
      if constexpr (!PRE) {
        #pragma unroll
        for (int j = 0; j < 4; ++j) {
          s8 th, tl;
          split8h(q0[j], q1[j], th, tl);
          *(s8*)(wb + sdstb + j * 1024) = th;
          *(s8*)(wb + sdstb + 4096 + j * 1024) = tl;
        }
      }
    }
    // boundary: counted vmcnt -- stage(c+1) proven complete (8 stage instrs,
    // then 16 A-loads issued after them); A prefetches stay in flight.
    if (do_stage) {
      __builtin_amdgcn_sched_barrier(0);
      if constexpr (PRE) {
        asm volatile("s_waitcnt vmcnt(16) lgkmcnt(0)");
      } else {
        asm volatile("s_waitcnt lgkmcnt(0)");
      }
      __builtin_amdgcn_s_barrier();
      __builtin_amdgcn_sched_barrier(0);
    }
  }

  // --- epilogue: per-wave logit scatter into buf0 region (safe: final chunk
  // reads buf1; all waves are past the chunk-6 barrier) ---
  float* lf = (float*)smem + w * 1088;  // 16 tok x 68 floats
  #pragma unroll
  for (int f = 0; f < 4; ++f)
    #pragma unroll
    for (int r = 0; r < 4; ++r)
      lf[(kg * 4 + r) * 68 + f * 16 + ec] = acc[f][r];

  if (lane < 16) {
    float v[64];
    #pragma unroll
    for (int i = 0; i < 16; ++i) {
      f4 q = *(const f4*)(lf + lane * 68 + 4 * i);
      v[4 * i + 0] = q.x; v[4 * i + 1] = q.y;
      v[4 * i + 2] = q.z; v[4 * i + 3] = q.w;
    }
    epilogue64(v, out + (size_t)(tok0 + w * 16 + lane) * 6);
  }
}

extern "C" void kernel_launch(void* const* d_in, const int* in_sizes, int n_in,
                              void* d_out, int out_size, void* d_ws, size_t ws_size,
                              hipStream_t stream) {
  const float* X = (const float*)d_in[0];
  const float* Wf = (const float*)d_in[1];
  float* out = (float*)d_out;
  const int T = in_sizes[0] / HD;  // 32768
  const int nblk = T / 128;        // 256 blocks of 512 threads (8 waves)

  const size_t need = (size_t)NE * HD * sizeof(u16);  // 256 KB per split
  if (ws_size >= 2 * need) {
    u16* Whi = (u16*)d_ws;
    u16* Wlo = Whi + (size_t)NE * HD;
    cvtW2<<<dim3(256), dim3(64), 0, stream>>>(Wf, Whi, Wlo);
    gateF<true><<<dim3(nblk), dim3(512), 0, stream>>>(X, Wf, Whi, Wlo, out);
  } else {
    gateF<false><<<dim3(nblk), dim3(512), 0, stream>>>(X, Wf, nullptr, nullptr, out);
  }
}